// Round 8
// baseline (232.656 us; speedup 1.0000x reference)
//
#include <hip/hip_runtime.h>
#include <hip/hip_bf16.h>
#include <string.h>

// MultiHeadAttention: B=1, L=4096, D=1024, H=16, HD=64, causal.
// R8 (= R7 with compile fix): attention with M=32 q/wave (halves per-q LDS
// B-fragment traffic, the measured bound), 512 blocks LPT-ordered (big chunks
// first) for dynamic balance at 2-3 blocks/CU; K-loop unrolled x2
// (compile-time buffer => all LDS addresses hoisted); causal mask peeled to
// the last 2 tiles; packed v_cvt_pk_bf16_f32 P-stores (memcpy-based bitcast,
// __builtin_bit_cast rejects __hip_bfloat162 on this ROCm).

typedef unsigned short ushort_t;
typedef __attribute__((ext_vector_type(8))) short short8;
typedef __attribute__((ext_vector_type(4))) float f32x4;

#define MFMA16(a, b, c) __builtin_amdgcn_mfma_f32_16x16x32_bf16(a, b, c, 0, 0, 0)

static constexpr int Lq = 4096;
static constexpr int Dm = 1024;
static constexpr int NH = 16;
static constexpr int HD = 64;
static constexpr int D3 = 3072;
static constexpr float SCALE_LOG2E = 0.125f * 1.44269504088896340736f;

__device__ __forceinline__ ushort_t f2bf(float f) {
    union { float f; unsigned int u; } x{f};
    unsigned int u = x.u;
    u += 0x7fffu + ((u >> 16) & 1u);   // RNE
    return (ushort_t)(u >> 16);
}

// packed fp32x2 -> bf16x2 (compiler emits v_cvt_pk_bf16_f32), RNE
__device__ __forceinline__ unsigned int cvtpk(float a, float b) {
    __hip_bfloat162 h = __float22bfloat162_rn(make_float2(a, b));
    unsigned int u;
    memcpy(&u, &h, 4);
    return u;
}

__device__ __forceinline__ void gl2lds16(const ushort_t* g, ushort_t* l) {
    __builtin_amdgcn_global_load_lds(
        (const __attribute__((address_space(1))) unsigned int*)g,
        (__attribute__((address_space(3))) unsigned int*)l, 16, 0, 0);
}

// ---------------- convert fp32 -> bf16 (flat) ----------------
__global__ void cvt_bf16(const float* __restrict__ in, ushort_t* __restrict__ out, int n) {
    int i = (blockIdx.x * blockDim.x + threadIdx.x) * 4;
    if (i + 3 < n) {
        float4 v = *(const float4*)&in[i];
        ushort_t r[4] = { f2bf(v.x), f2bf(v.y), f2bf(v.z), f2bf(v.w) };
        *(uint2*)&out[i] = *(uint2*)r;
    }
}

// ---------------- transpose-convert W (K x N fp32) -> Wt (N x K bf16) ----------------
__global__ void wtrans(const float* __restrict__ W, ushort_t* __restrict__ Wt, int K, int N) {
    __shared__ float tile[32][33];
    int nb = blockIdx.x * 32, kb = blockIdx.y * 32;
    int tx = threadIdx.x, ty = threadIdx.y;
    for (int j = 0; j < 32; j += 8)
        tile[ty + j][tx] = W[(size_t)(kb + ty + j) * N + nb + tx];
    __syncthreads();
    for (int j = 0; j < 32; j += 8)
        Wt[(size_t)(nb + ty + j) * K + kb + tx] = f2bf(tile[tx][ty + j]);
}

// ---------------- transpose V -> Vt[h][d][key-permuted l] ----------------
// Within each 64-key block, store key k at column c' = (k&15)*4 + (k>>4)&3.
// Matches attention's P column order c' = l16*4 + s (key = s*16 + l16).
__global__ void vtrans(const ushort_t* __restrict__ qkv, ushort_t* __restrict__ Vt) {
    __shared__ ushort_t tile[32][33];
    int h  = blockIdx.z;
    int lb = blockIdx.x * 32;
    int db = blockIdx.y * 32;
    int tx = threadIdx.x, ty = threadIdx.y;
    for (int j = 0; j < 32; j += 8)
        tile[ty + j][tx] = qkv[(size_t)(lb + ty + j) * D3 + 2048 + h * HD + db + tx];
    __syncthreads();
    const int key  = lb + tx;
    const int k63  = key & 63;
    const int cp   = (key & ~63) + ((k63 & 15) * 4 + (k63 >> 4));
    for (int j = 0; j < 32; j += 8)
        Vt[(size_t)h * HD * Lq + (size_t)(db + ty + j) * Lq + cp] = tile[tx][ty + j];
}

// ---------------- MFMA GEMM (m97 structure): C = A * Bt^T + bias ----------------
template <bool OUT_BF16, bool QSCALE>
__global__ void __launch_bounds__(256)
gemm_bt(const ushort_t* __restrict__ A, const ushort_t* __restrict__ Bt,
        const float* __restrict__ bias, void* __restrict__ C,
        int M, int N, int K) {
    __shared__ alignas(16) ushort_t Alds[128 * 32];
    __shared__ alignas(16) ushort_t Blds[128 * 32];
    const int tid  = threadIdx.x;
    const int lane = tid & 63;
    const int w    = tid >> 6;
    const int quad = lane >> 4;
    const int l16  = lane & 15;
    const int mbase = blockIdx.x * 128;
    const int nbase = blockIdx.y * 128;
    const int moff  = (w >> 1) * 64;
    const int noff  = (w & 1) * 64;

    f32x4 acc[4][4] = {};

    for (int kb = 0; kb < K; kb += 32) {
        __syncthreads();
        #pragma unroll
        for (int c = 0; c < 2; c++) {
            int id  = w * 128 + c * 64 + lane;
            int row = id >> 2, col = (id & 3) * 8;
            gl2lds16(&A[(size_t)(mbase + row) * K + kb + col], &Alds[(size_t)(w * 128 + c * 64) * 8]);
            gl2lds16(&Bt[(size_t)(nbase + row) * K + kb + col], &Blds[(size_t)(w * 128 + c * 64) * 8]);
        }
        __syncthreads();
        short8 a[4], b[4];
        #pragma unroll
        for (int m = 0; m < 4; m++)
            a[m] = *(const short8*)&Alds[(moff + m * 16 + l16) * 32 + quad * 8];
        #pragma unroll
        for (int n = 0; n < 4; n++)
            b[n] = *(const short8*)&Blds[(noff + n * 16 + l16) * 32 + quad * 8];
        #pragma unroll
        for (int m = 0; m < 4; m++)
            #pragma unroll
            for (int n = 0; n < 4; n++)
                acc[m][n] = MFMA16(a[m], b[n], acc[m][n]);
    }

    #pragma unroll
    for (int m = 0; m < 4; m++)
        #pragma unroll
        for (int n = 0; n < 4; n++)
            #pragma unroll
            for (int r = 0; r < 4; r++) {
                int row = mbase + moff + m * 16 + quad * 4 + r;
                int col = nbase + noff + n * 16 + l16;
                float v = acc[m][n][r] + bias[col];
                if (QSCALE && col < Dm) v *= SCALE_LOG2E;
                if (OUT_BF16)
                    ((ushort_t*)C)[(size_t)row * N + col] = f2bf(v);
                else
                    ((float*)C)[(size_t)row * N + col] = v;
            }
}

// ---------------- flash attention (R7/R8) ----------------
// grid 512 = 32 chunks x 16 heads; head = bid & 15 (XCD pin);
// c = 31 - (bid>>4): longest blocks (nt = 2c+2 tiles) dispatch first (LPT).
// block 256 = 4 waves x 32 queries (M=32: two 16-row A-frags per wave).
// K/V double-buffered LDS via global_load_lds (XOR swizzle); main loop
// unrolled x2 (compile-time buffer), causal mask only on the last 2 tiles.
__global__ void __launch_bounds__(256, 2)
attn_fwd(const ushort_t* __restrict__ qkv, const ushort_t* __restrict__ Vt,
         ushort_t* __restrict__ O) {
    __shared__ alignas(16) ushort_t Kl[2][64 * 64];
    __shared__ alignas(16) ushort_t Vl[2][64 * 64];
    __shared__ alignas(16) ushort_t Pl[4 * 32 * 72];

    const int tid  = threadIdx.x;
    const int lane = tid & 63;
    const int w    = tid >> 6;          // [0,4)
    const int quad = lane >> 4;
    const int l16  = lane & 15;
    const int bid  = blockIdx.x;
    const int h    = bid & 15;
    const int c    = 31 - (bid >> 4);   // [0,32), descending work
    const int qc   = c * 128;
    const int qw   = qc + w * 32;       // wave's 32 query rows
    ushort_t* pw   = Pl + w * 32 * 72;
    const float NEG_INF = -__builtin_inff();
    const int sw   = l16 & 7;

    const short bf1 = (short)0x3F80;
    const short8 ones = { bf1, bf1, bf1, bf1, bf1, bf1, bf1, bf1 };

    const ushort_t* kbase = qkv + Dm + h * HD;           // K rows, stride D3
    const ushort_t* vbase = Vt + (size_t)h * HD * Lq;    // V^T rows, stride Lq

    // Q A-fragments (exp2-domain, pre-scaled in GEMM epilogue)
    short8 qf[2][2];
    #pragma unroll
    for (int m = 0; m < 2; m++) {
        const ushort_t* qr = qkv + (size_t)(qw + m * 16 + l16) * D3 + h * HD;
        qf[m][0] = *(const short8*)(qr + quad * 8);
        qf[m][1] = *(const short8*)(qr + 32 + quad * 8);
    }

    f32x4 o[2][4] = {};
    f32x4 lacc[2] = {};

    // loop-invariant LDS fragment offsets (shared by K and V reads)
    int kvo[4][2];
    #pragma unroll
    for (int s = 0; s < 4; s++)
        #pragma unroll
        for (int kh = 0; kh < 2; kh++)
            kvo[s][kh] = (s * 16 + l16) * 64 + (((kh * 4 + quad) ^ sw) * 8);

    // staging geometry: 512 granules/tile; thread covers granules g0, g0+64.
    // granule g -> tile row g>>3, swizzled source col (g&7)^(row&7).
    const int g0 = w * 128 + lane;
    const int r0 = g0 >> 3, c0 = (g0 & 7) ^ (r0 & 7);
    const int g1 = g0 + 64;
    const int r1 = g1 >> 3, c1 = (g1 & 7) ^ (r1 & 7);
    const ushort_t* ks0 = kbase + (size_t)r0 * D3 + c0 * 8;
    const ushort_t* ks1 = kbase + (size_t)r1 * D3 + c1 * 8;
    const ushort_t* vs0 = vbase + (size_t)r0 * Lq + c0 * 8;
    const ushort_t* vs1 = vbase + (size_t)r1 * Lq + c1 * 8;

    auto stage = [&](int t, int b) {
        const size_t ko = (size_t)t * 64 * D3;
        const int    vo = t * 64;
        gl2lds16(ks0 + ko, &Kl[b][w * 1024]);
        gl2lds16(ks1 + ko, &Kl[b][w * 1024 + 512]);
        gl2lds16(vs0 + vo, &Vl[b][w * 1024]);
        gl2lds16(vs1 + vo, &Vl[b][w * 1024 + 512]);
    };

    auto compute = [&](const ushort_t* Kb, const ushort_t* Vb, int k0, bool domask) {
        short8 kf[4][2];
        #pragma unroll
        for (int s = 0; s < 4; s++)
            #pragma unroll
            for (int kh = 0; kh < 2; kh++)
                kf[s][kh] = *(const short8*)&Kb[kvo[s][kh]];

        f32x4 st[2][4];
        #pragma unroll
        for (int m = 0; m < 2; m++)
            #pragma unroll
            for (int s = 0; s < 4; s++) {
                f32x4 t = {};
                t = MFMA16(qf[m][0], kf[s][0], t);
                t = MFMA16(qf[m][1], kf[s][1], t);
                st[m][s] = t;
            }

        #pragma unroll
        for (int m = 0; m < 2; m++)
            #pragma unroll
            for (int r = 0; r < 4; r++) {
                float e[4];
                #pragma unroll
                for (int s = 0; s < 4; s++) {
                    float v = st[m][s][r];
                    if (domask) {
                        const int qg = qw + m * 16 + quad * 4 + r;
                        if (k0 + s * 16 + l16 > qg) v = NEG_INF;
                    }
                    e[s] = __builtin_amdgcn_exp2f(v);
                }
                uint2 pk = { cvtpk(e[0], e[1]), cvtpk(e[2], e[3]) };
                *(uint2*)&pw[(m * 16 + quad * 4 + r) * 72 + l16 * 4] = pk;
            }

        short8 pf[2][2];
        #pragma unroll
        for (int m = 0; m < 2; m++)
            #pragma unroll
            for (int kh = 0; kh < 2; kh++)
                pf[m][kh] = *(const short8*)&pw[(m * 16 + l16) * 72 + kh * 32 + quad * 8];
        #pragma unroll
        for (int m = 0; m < 2; m++) {
            lacc[m] = MFMA16(pf[m][0], ones, lacc[m]);
            lacc[m] = MFMA16(pf[m][1], ones, lacc[m]);
        }

        short8 vf[4][2];
        #pragma unroll
        for (int t = 0; t < 4; t++)
            #pragma unroll
            for (int kh = 0; kh < 2; kh++)
                vf[t][kh] = *(const short8*)&Vb[kvo[t][kh]];
        #pragma unroll
        for (int m = 0; m < 2; m++)
            #pragma unroll
            for (int t = 0; t < 4; t++) {
                o[m][t] = MFMA16(pf[m][0], vf[t][0], o[m][t]);
                o[m][t] = MFMA16(pf[m][1], vf[t][1], o[m][t]);
            }
    };

    // prologue: tile 0 -> buf 0
    stage(0, 0);

    // main loop: tiles 0..2c-1 (all keys < qc: unmasked), unrolled x2
    for (int kt2 = 0; kt2 < c; kt2++) {
        __syncthreads();
        stage(2 * kt2 + 1, 1);
        compute(Kl[0], Vl[0], (2 * kt2) * 64, false);
        __syncthreads();
        stage(2 * kt2 + 2, 0);
        compute(Kl[1], Vl[1], (2 * kt2 + 1) * 64, false);
    }
    // tail: tiles 2c (buf0) and 2c+1 (buf1), masked
    __syncthreads();
    stage(2 * c + 1, 1);
    compute(Kl[0], Vl[0], 2 * c * 64, true);
    __syncthreads();
    compute(Kl[1], Vl[1], 2 * c * 64 + 64, true);

    // epilogue
    #pragma unroll
    for (int m = 0; m < 2; m++)
        #pragma unroll
        for (int r = 0; r < 4; r++) {
            const float inv = 1.0f / lacc[m][r];
            ushort_t* orow = O + (size_t)(qw + m * 16 + quad * 4 + r) * Dm + h * HD;
            #pragma unroll
            for (int t = 0; t < 4; t++)
                orow[t * 16 + l16] = f2bf(o[m][t][r] * inv);
        }
}

// ---------------- launch ----------------
extern "C" void kernel_launch(void* const* d_in, const int* in_sizes, int n_in,
                              void* d_out, int out_size, void* d_ws, size_t ws_size,
                              hipStream_t stream) {
    const float* X     = (const float*)d_in[0];
    const float* Wqkv  = (const float*)d_in[1];
    const float* bqkv  = (const float*)d_in[2];
    const float* Wproj = (const float*)d_in[3];
    const float* bproj = (const float*)d_in[4];
    float* out = (float*)d_out;

    ushort_t* ws     = (ushort_t*)d_ws;
    ushort_t* Xb     = ws;                               // 4096x1024
    ushort_t* WqkvT  = Xb + (size_t)Lq * Dm;             // 3072x1024
    ushort_t* WprojT = WqkvT + (size_t)D3 * Dm;          // 1024x1024
    ushort_t* qkvB   = WprojT + (size_t)Dm * Dm;         // 4096x3072
    ushort_t* VtB    = qkvB + (size_t)Lq * D3;           // 16x64x4096
    ushort_t* Ob     = VtB + (size_t)NH * HD * Lq;       // 4096x1024

    cvt_bf16<<<(Lq * Dm / 4 + 255) / 256, 256, 0, stream>>>(X, Xb, Lq * Dm);
    wtrans<<<dim3(D3 / 32, Dm / 32), dim3(32, 8), 0, stream>>>(Wqkv, WqkvT, Dm, D3);
    wtrans<<<dim3(Dm / 32, Dm / 32), dim3(32, 8), 0, stream>>>(Wproj, WprojT, Dm, Dm);

    gemm_bt<true, true><<<dim3(Lq / 128, D3 / 128), 256, 0, stream>>>(
        Xb, WqkvT, bqkv, (void*)qkvB, Lq, D3, Dm);

    vtrans<<<dim3(Lq / 32, HD / 32, NH), dim3(32, 8), 0, stream>>>(qkvB, VtB);

    attn_fwd<<<dim3(512), 256, 0, stream>>>(qkvB, VtB, Ob);

    gemm_bt<false, false><<<dim3(Lq / 128, Dm / 128), 256, 0, stream>>>(
        Ob, WprojT, bproj, (void*)out, Lq, Dm, Dm);
}

// Round 9
// 222.549 us; speedup vs baseline: 1.0454x; 1.0454x over previous
//
#include <hip/hip_runtime.h>
#include <hip/hip_bf16.h>
#include <string.h>

// MultiHeadAttention: B=1, L=4096, D=1024, H=16, HD=64, causal.
// R9: attention = 8-wave blocks (2 waves/SIMD, the R8 regression fix) x M=32
// q/wave (the LDS-traffic fix) x even/odd key-split with LDS sum-merge (valid
// in no-max exp2 domain) x sel-pairing (c, 31-c) => grid 256, 1 block/CU,
// perfectly uniform 34 rounds/block. K/V staged 4 tiles/round by
// global_load_lds (XOR swizzle) after the loop-top barrier; mask only in the
// final round.

typedef unsigned short ushort_t;
typedef __attribute__((ext_vector_type(8))) short short8;
typedef __attribute__((ext_vector_type(4))) float f32x4;

#define MFMA16(a, b, c) __builtin_amdgcn_mfma_f32_16x16x32_bf16(a, b, c, 0, 0, 0)

static constexpr int Lq = 4096;
static constexpr int Dm = 1024;
static constexpr int NH = 16;
static constexpr int HD = 64;
static constexpr int D3 = 3072;
static constexpr float SCALE_LOG2E = 0.125f * 1.44269504088896340736f;

__device__ __forceinline__ ushort_t f2bf(float f) {
    union { float f; unsigned int u; } x{f};
    unsigned int u = x.u;
    u += 0x7fffu + ((u >> 16) & 1u);   // RNE
    return (ushort_t)(u >> 16);
}

// packed fp32x2 -> bf16x2 (compiler emits v_cvt_pk_bf16_f32), RNE
__device__ __forceinline__ unsigned int cvtpk(float a, float b) {
    __hip_bfloat162 h = __float22bfloat162_rn(make_float2(a, b));
    unsigned int u;
    memcpy(&u, &h, 4);
    return u;
}

__device__ __forceinline__ void gl2lds16(const ushort_t* g, ushort_t* l) {
    __builtin_amdgcn_global_load_lds(
        (const __attribute__((address_space(1))) unsigned int*)g,
        (__attribute__((address_space(3))) unsigned int*)l, 16, 0, 0);
}

// ---------------- convert fp32 -> bf16 (flat) ----------------
__global__ void cvt_bf16(const float* __restrict__ in, ushort_t* __restrict__ out, int n) {
    int i = (blockIdx.x * blockDim.x + threadIdx.x) * 4;
    if (i + 3 < n) {
        float4 v = *(const float4*)&in[i];
        ushort_t r[4] = { f2bf(v.x), f2bf(v.y), f2bf(v.z), f2bf(v.w) };
        *(uint2*)&out[i] = *(uint2*)r;
    }
}

// ---------------- transpose-convert W (K x N fp32) -> Wt (N x K bf16) ----------------
__global__ void wtrans(const float* __restrict__ W, ushort_t* __restrict__ Wt, int K, int N) {
    __shared__ float tile[32][33];
    int nb = blockIdx.x * 32, kb = blockIdx.y * 32;
    int tx = threadIdx.x, ty = threadIdx.y;
    for (int j = 0; j < 32; j += 8)
        tile[ty + j][tx] = W[(size_t)(kb + ty + j) * N + nb + tx];
    __syncthreads();
    for (int j = 0; j < 32; j += 8)
        Wt[(size_t)(nb + ty + j) * K + kb + tx] = f2bf(tile[tx][ty + j]);
}

// ---------------- transpose V -> Vt[h][d][key-permuted l] ----------------
// Within each 64-key block, store key k at column c' = (k&15)*4 + (k>>4)&3.
// Matches attention's P column order c' = l16*4 + s (key = s*16 + l16).
__global__ void vtrans(const ushort_t* __restrict__ qkv, ushort_t* __restrict__ Vt) {
    __shared__ ushort_t tile[32][33];
    int h  = blockIdx.z;
    int lb = blockIdx.x * 32;
    int db = blockIdx.y * 32;
    int tx = threadIdx.x, ty = threadIdx.y;
    for (int j = 0; j < 32; j += 8)
        tile[ty + j][tx] = qkv[(size_t)(lb + ty + j) * D3 + 2048 + h * HD + db + tx];
    __syncthreads();
    const int key  = lb + tx;
    const int k63  = key & 63;
    const int cp   = (key & ~63) + ((k63 & 15) * 4 + (k63 >> 4));
    for (int j = 0; j < 32; j += 8)
        Vt[(size_t)h * HD * Lq + (size_t)(db + ty + j) * Lq + cp] = tile[tx][ty + j];
}

// ---------------- MFMA GEMM (m97 structure): C = A * Bt^T + bias ----------------
template <bool OUT_BF16, bool QSCALE>
__global__ void __launch_bounds__(256)
gemm_bt(const ushort_t* __restrict__ A, const ushort_t* __restrict__ Bt,
        const float* __restrict__ bias, void* __restrict__ C,
        int M, int N, int K) {
    __shared__ alignas(16) ushort_t Alds[128 * 32];
    __shared__ alignas(16) ushort_t Blds[128 * 32];
    const int tid  = threadIdx.x;
    const int lane = tid & 63;
    const int w    = tid >> 6;
    const int quad = lane >> 4;
    const int l16  = lane & 15;
    const int mbase = blockIdx.x * 128;
    const int nbase = blockIdx.y * 128;
    const int moff  = (w >> 1) * 64;
    const int noff  = (w & 1) * 64;

    f32x4 acc[4][4] = {};

    for (int kb = 0; kb < K; kb += 32) {
        __syncthreads();
        #pragma unroll
        for (int c = 0; c < 2; c++) {
            int id  = w * 128 + c * 64 + lane;
            int row = id >> 2, col = (id & 3) * 8;
            gl2lds16(&A[(size_t)(mbase + row) * K + kb + col], &Alds[(size_t)(w * 128 + c * 64) * 8]);
            gl2lds16(&Bt[(size_t)(nbase + row) * K + kb + col], &Blds[(size_t)(w * 128 + c * 64) * 8]);
        }
        __syncthreads();
        short8 a[4], b[4];
        #pragma unroll
        for (int m = 0; m < 4; m++)
            a[m] = *(const short8*)&Alds[(moff + m * 16 + l16) * 32 + quad * 8];
        #pragma unroll
        for (int n = 0; n < 4; n++)
            b[n] = *(const short8*)&Blds[(noff + n * 16 + l16) * 32 + quad * 8];
        #pragma unroll
        for (int m = 0; m < 4; m++)
            #pragma unroll
            for (int n = 0; n < 4; n++)
                acc[m][n] = MFMA16(a[m], b[n], acc[m][n]);
    }

    #pragma unroll
    for (int m = 0; m < 4; m++)
        #pragma unroll
        for (int n = 0; n < 4; n++)
            #pragma unroll
            for (int r = 0; r < 4; r++) {
                int row = mbase + moff + m * 16 + quad * 4 + r;
                int col = nbase + noff + n * 16 + l16;
                float v = acc[m][n][r] + bias[col];
                if (QSCALE && col < Dm) v *= SCALE_LOG2E;
                if (OUT_BF16)
                    ((ushort_t*)C)[(size_t)row * N + col] = f2bf(v);
                else
                    ((float*)C)[(size_t)row * N + col] = v;
            }
}

// ---------------- flash attention (R9) ----------------
// grid 256 = 16 pairs x 16 heads; head = bid & 15 (XCD pin); p = bid >> 4.
// block 512 = 8 waves: half = w>>2 (even/odd 64-key tiles), sub = w&3
// (q rows qc + sub*32). sel 0: chunk p; sel 1: chunk 31-p => 34 rounds
// total per block (uniform). Per round: stage 4 tiles (Ke,Ko,Ve,Vo) for
// round r+1 after the barrier, compute tile (2r+half). Halves sum-merge
// (O, l) through LDS per sel (no max bias => same exp2 domain).
__global__ void __launch_bounds__(512, 2)
attn_fwd(const ushort_t* __restrict__ qkv, const ushort_t* __restrict__ Vt,
         ushort_t* __restrict__ O) {
    __shared__ alignas(16) ushort_t Kl[2][2][64 * 64];   // [half][buf]
    __shared__ alignas(16) ushort_t Vl[2][2][64 * 64];
    __shared__ alignas(16) ushort_t Pl[8 * 32 * 72];
    __shared__ alignas(16) float    Ml[256 * 41];        // merge: pitch 41 (bank spread)

    const int tid  = threadIdx.x;
    const int lane = tid & 63;
    const int w    = tid >> 6;          // [0,8)
    const int half = w >> 2;            // 0: even tiles, 1: odd tiles
    const int sub  = w & 3;             // q sub-chunk
    const int quad = lane >> 4;
    const int l16  = lane & 15;
    const int bid  = blockIdx.x;
    const int h    = bid & 15;
    const int p    = bid >> 4;          // [0,16)
    ushort_t* pw   = Pl + w * 32 * 72;
    const float NEG_INF = -__builtin_inff();
    const int sw   = l16 & 7;

    const short bf1 = (short)0x3F80;
    const short8 ones = { bf1, bf1, bf1, bf1, bf1, bf1, bf1, bf1 };

    const ushort_t* kbase = qkv + Dm + h * HD;           // K rows, stride D3
    const ushort_t* vbase = Vt + (size_t)h * HD * Lq;    // V^T rows, stride Lq

    // loop-invariant LDS fragment offsets (shared by K and V reads)
    int kvo[4][2];
    #pragma unroll
    for (int s = 0; s < 4; s++)
        #pragma unroll
        for (int kh = 0; kh < 2; kh++)
            kvo[s][kh] = (s * 16 + l16) * 64 + (((kh * 4 + quad) ^ sw) * 8);

    // staging geometry: each tile = 512 granules of 16B; thread covers
    // granule tid (wave w spans granules w*64..+63 -> LDS base w*512 elems).
    // granule g -> tile row g>>3, swizzled source col (g&7)^(row&7).
    const int rr = tid >> 3, cc = (tid & 7) ^ (rr & 7);
    const ushort_t* kse = kbase + (size_t)rr * D3 + cc * 8;   // K row rr
    const ushort_t* vse = vbase + (size_t)rr * Lq + cc * 8;   // V^T row rr (d)
    const int dstoff = w * 512;

    for (int sel = 0; sel < 2; sel++) {
        const int c      = sel ? (31 - p) : p;
        const int qc     = c * 128;
        const int rounds = c + 1;           // tiles 2r (even), 2r+1 (odd)
        const int qw     = qc + sub * 32;   // wave's 32 query rows

        // Q A-fragments (exp2-domain, pre-scaled in GEMM epilogue)
        short8 qf[2][2];
        #pragma unroll
        for (int m = 0; m < 2; m++) {
            const ushort_t* qr = qkv + (size_t)(qw + m * 16 + l16) * D3 + h * HD;
            qf[m][0] = *(const short8*)(qr + quad * 8);
            qf[m][1] = *(const short8*)(qr + 32 + quad * 8);
        }

        f32x4 o[2][4] = {};
        f32x4 lacc[2] = {};

        // incremental staging sources (advance 128 keys per round)
        const ushort_t* kp = kse;
        const ushort_t* vp = vse;

        auto stage = [&](int b) {
            gl2lds16(kp,            &Kl[0][b][dstoff]);
            gl2lds16(kp + 64 * D3,  &Kl[1][b][dstoff]);
            gl2lds16(vp,            &Vl[0][b][dstoff]);
            gl2lds16(vp + 64,       &Vl[1][b][dstoff]);
            kp += (size_t)128 * D3;
            vp += 128;
        };

        // prologue: round 0 -> buf 0
        stage(0);

        for (int r = 0; r < rounds; r++) {
            const int buf = r & 1;
            __syncthreads();            // round r staged & visible
            if (r + 1 < rounds) stage(buf ^ 1);

            const ushort_t* Kb = &Kl[half][buf][0];
            const ushort_t* Vb = &Vl[half][buf][0];
            const int k0 = (2 * r + half) * 64;
            const bool domask = (r == rounds - 1);

            short8 kf[4][2];
            #pragma unroll
            for (int s = 0; s < 4; s++)
                #pragma unroll
                for (int kh = 0; kh < 2; kh++)
                    kf[s][kh] = *(const short8*)&Kb[kvo[s][kh]];

            f32x4 st[2][4];
            #pragma unroll
            for (int m = 0; m < 2; m++)
                #pragma unroll
                for (int s = 0; s < 4; s++) {
                    f32x4 t = {};
                    t = MFMA16(qf[m][0], kf[s][0], t);
                    t = MFMA16(qf[m][1], kf[s][1], t);
                    st[m][s] = t;
                }

            #pragma unroll
            for (int m = 0; m < 2; m++)
                #pragma unroll
                for (int r4 = 0; r4 < 4; r4++) {
                    float e[4];
                    #pragma unroll
                    for (int s = 0; s < 4; s++) {
                        float v = st[m][s][r4];
                        if (domask) {
                            const int qg = qw + m * 16 + quad * 4 + r4;
                            if (k0 + s * 16 + l16 > qg) v = NEG_INF;
                        }
                        e[s] = __builtin_amdgcn_exp2f(v);
                    }
                    uint2 pk = { cvtpk(e[0], e[1]), cvtpk(e[2], e[3]) };
                    *(uint2*)&pw[(m * 16 + quad * 4 + r4) * 72 + l16 * 4] = pk;
                }

            short8 pf[2][2];
            #pragma unroll
            for (int m = 0; m < 2; m++)
                #pragma unroll
                for (int kh = 0; kh < 2; kh++)
                    pf[m][kh] = *(const short8*)&pw[(m * 16 + l16) * 72 + kh * 32 + quad * 8];
            #pragma unroll
            for (int m = 0; m < 2; m++) {
                lacc[m] = MFMA16(pf[m][0], ones, lacc[m]);
                lacc[m] = MFMA16(pf[m][1], ones, lacc[m]);
            }

            short8 vf[4][2];
            #pragma unroll
            for (int t = 0; t < 4; t++)
                #pragma unroll
                for (int kh = 0; kh < 2; kh++)
                    vf[t][kh] = *(const short8*)&Vb[kvo[t][kh]];
            #pragma unroll
            for (int m = 0; m < 2; m++)
                #pragma unroll
                for (int t = 0; t < 4; t++) {
                    o[m][t] = MFMA16(pf[m][0], vf[t][0], o[m][t]);
                    o[m][t] = MFMA16(pf[m][1], vf[t][1], o[m][t]);
                }
        }

        // merge halves (sum in exp2 domain), then even half normalizes+stores
        __syncthreads();
        if (half == 1) {
            float* dst = Ml + (sub * 64 + lane) * 41;
            #pragma unroll
            for (int m = 0; m < 2; m++)
                #pragma unroll
                for (int t = 0; t < 4; t++)
                    *(f32x4*)(dst + m * 16 + t * 4) = o[m][t];
            *(f32x4*)(dst + 32) = lacc[0];
            *(f32x4*)(dst + 36) = lacc[1];
        }
        __syncthreads();
        if (half == 0) {
            const float* src = Ml + (sub * 64 + lane) * 41;
            #pragma unroll
            for (int m = 0; m < 2; m++)
                #pragma unroll
                for (int t = 0; t < 4; t++)
                    o[m][t] += *(const f32x4*)(src + m * 16 + t * 4);
            lacc[0] += *(const f32x4*)(src + 32);
            lacc[1] += *(const f32x4*)(src + 36);
            #pragma unroll
            for (int m = 0; m < 2; m++)
                #pragma unroll
                for (int r4 = 0; r4 < 4; r4++) {
                    const float inv = 1.0f / lacc[m][r4];
                    ushort_t* orow = O + (size_t)(qw + m * 16 + quad * 4 + r4) * Dm + h * HD;
                    #pragma unroll
                    for (int t = 0; t < 4; t++)
                        orow[t * 16 + l16] = f2bf(o[m][t][r4] * inv);
                }
        }
        __syncthreads();   // Ml consumed before next sel reuses anything
    }
}

// ---------------- launch ----------------
extern "C" void kernel_launch(void* const* d_in, const int* in_sizes, int n_in,
                              void* d_out, int out_size, void* d_ws, size_t ws_size,
                              hipStream_t stream) {
    const float* X     = (const float*)d_in[0];
    const float* Wqkv  = (const float*)d_in[1];
    const float* bqkv  = (const float*)d_in[2];
    const float* Wproj = (const float*)d_in[3];
    const float* bproj = (const float*)d_in[4];
    float* out = (float*)d_out;

    ushort_t* ws     = (ushort_t*)d_ws;
    ushort_t* Xb     = ws;                               // 4096x1024
    ushort_t* WqkvT  = Xb + (size_t)Lq * Dm;             // 3072x1024
    ushort_t* WprojT = WqkvT + (size_t)D3 * Dm;          // 1024x1024
    ushort_t* qkvB   = WprojT + (size_t)Dm * Dm;         // 4096x3072
    ushort_t* VtB    = qkvB + (size_t)Lq * D3;           // 16x64x4096
    ushort_t* Ob     = VtB + (size_t)NH * HD * Lq;       // 4096x1024

    cvt_bf16<<<(Lq * Dm / 4 + 255) / 256, 256, 0, stream>>>(X, Xb, Lq * Dm);
    wtrans<<<dim3(D3 / 32, Dm / 32), dim3(32, 8), 0, stream>>>(Wqkv, WqkvT, Dm, D3);
    wtrans<<<dim3(Dm / 32, Dm / 32), dim3(32, 8), 0, stream>>>(Wproj, WprojT, Dm, Dm);

    gemm_bt<true, true><<<dim3(Lq / 128, D3 / 128), 256, 0, stream>>>(
        Xb, WqkvT, bqkv, (void*)qkvB, Lq, D3, Dm);

    vtrans<<<dim3(Lq / 32, HD / 32, NH), dim3(32, 8), 0, stream>>>(qkvB, VtB);

    attn_fwd<<<dim3(256), 512, 0, stream>>>(qkvB, VtB, Ob);

    gemm_bt<false, false><<<dim3(Lq / 128, Dm / 128), 256, 0, stream>>>(
        Ob, WprojT, bproj, (void*)out, Lq, Dm, Dm);
}

// Round 10
// 214.377 us; speedup vs baseline: 1.0853x; 1.0381x over previous
//
#include <hip/hip_runtime.h>
#include <hip/hip_bf16.h>
#include <string.h>

// MultiHeadAttention: B=1, L=4096, D=1024, H=16, HD=64, causal.
// R10: launch-chain compression 7 -> 4 kernels (residual has been ~140us and
// invariant to GEMM speed since R1 => fixed overhead dominated):
//   prep (cvt + both wtrans fused) -> gemm_qkv (V-transpose fused into
//   epilogue, scattered bf16 stores) -> attn (unchanged R9) -> gemm_proj
//   (128x64 tiles, 512 blocks = 2/CU for occupancy; was 256 = 1/CU).

typedef unsigned short ushort_t;
typedef __attribute__((ext_vector_type(8))) short short8;
typedef __attribute__((ext_vector_type(4))) float f32x4;

#define MFMA16(a, b, c) __builtin_amdgcn_mfma_f32_16x16x32_bf16(a, b, c, 0, 0, 0)

static constexpr int Lq = 4096;
static constexpr int Dm = 1024;
static constexpr int NH = 16;
static constexpr int HD = 64;
static constexpr int D3 = 3072;
static constexpr float SCALE_LOG2E = 0.125f * 1.44269504088896340736f;

__device__ __forceinline__ ushort_t f2bf(float f) {
    union { float f; unsigned int u; } x{f};
    unsigned int u = x.u;
    u += 0x7fffu + ((u >> 16) & 1u);   // RNE
    return (ushort_t)(u >> 16);
}

// packed fp32x2 -> bf16x2 (compiler emits v_cvt_pk_bf16_f32), RNE
__device__ __forceinline__ unsigned int cvtpk(float a, float b) {
    __hip_bfloat162 h = __float22bfloat162_rn(make_float2(a, b));
    unsigned int u;
    memcpy(&u, &h, 4);
    return u;
}

__device__ __forceinline__ void gl2lds16(const ushort_t* g, ushort_t* l) {
    __builtin_amdgcn_global_load_lds(
        (const __attribute__((address_space(1))) unsigned int*)g,
        (__attribute__((address_space(3))) unsigned int*)l, 16, 0, 0);
}

// ---------------- prep: cvt X->bf16 + transpose-convert both W ----------------
// grid 8192: [0,4096) cvt; [4096,7168) Wqkv trans; [7168,8192) Wproj trans.
__global__ void __launch_bounds__(256)
prep(const float* __restrict__ X, const float* __restrict__ Wqkv,
     const float* __restrict__ Wproj, ushort_t* __restrict__ Xb,
     ushort_t* __restrict__ WqkvT, ushort_t* __restrict__ WprojT) {
    __shared__ float tile[32][33];
    const int bid = blockIdx.x, tid = threadIdx.x;
    if (bid < 4096) {
        int i = (bid * 256 + tid) * 4;
        float4 v = *(const float4*)&X[i];
        ushort_t r[4] = { f2bf(v.x), f2bf(v.y), f2bf(v.z), f2bf(v.w) };
        *(uint2*)&Xb[i] = *(uint2*)r;
        return;
    }
    const float* W; ushort_t* Wt; int Nd, nb, kb;
    if (bid < 7168) {
        int b = bid - 4096; W = Wqkv;  Wt = WqkvT;  Nd = 3072;
        nb = (b % 96) * 32; kb = (b / 96) * 32;
    } else {
        int b = bid - 7168; W = Wproj; Wt = WprojT; Nd = 1024;
        nb = (b % 32) * 32; kb = (b / 32) * 32;
    }
    const int tx = tid & 31, ty = tid >> 5;
    for (int j = 0; j < 32; j += 8)
        tile[ty + j][tx] = W[(size_t)(kb + ty + j) * Nd + nb + tx];
    __syncthreads();
    for (int j = 0; j < 32; j += 8)
        Wt[(size_t)(nb + ty + j) * Dm + kb + tx] = f2bf(tile[tx][ty + j]);
}

// ---------------- QKV GEMM with fused V-transpose epilogue ----------------
// C = Xb * WqkvT^T + bqkv. cols [0,1024): *SCALE_LOG2E -> qkvB (Q);
// cols [1024,2048): -> qkvB (K); cols [2048,3072): scattered bf16 stores to
// Vt[h][d][perm64(key)] (perm: key k -> (k&15)*4 + (k>>4)&3 within 64-block,
// matching attention's P column order). qkv V region never written/read.
__global__ void __launch_bounds__(256)
gemm_qkv(const ushort_t* __restrict__ A, const ushort_t* __restrict__ Bt,
         const float* __restrict__ bias, ushort_t* __restrict__ Cq,
         ushort_t* __restrict__ Vt) {
    __shared__ alignas(16) ushort_t Alds[128 * 32];
    __shared__ alignas(16) ushort_t Blds[128 * 32];
    const int tid  = threadIdx.x;
    const int lane = tid & 63;
    const int w    = tid >> 6;
    const int quad = lane >> 4;
    const int l16  = lane & 15;
    const int mbase = blockIdx.x * 128;
    const int nbase = blockIdx.y * 128;
    const int moff  = (w >> 1) * 64;
    const int noff  = (w & 1) * 64;
    const int K = Dm;

    f32x4 acc[4][4] = {};

    for (int kb = 0; kb < K; kb += 32) {
        __syncthreads();
        #pragma unroll
        for (int c = 0; c < 2; c++) {
            int id  = w * 128 + c * 64 + lane;
            int row = id >> 2, col = (id & 3) * 8;
            gl2lds16(&A[(size_t)(mbase + row) * K + kb + col], &Alds[(size_t)(w * 128 + c * 64) * 8]);
            gl2lds16(&Bt[(size_t)(nbase + row) * K + kb + col], &Blds[(size_t)(w * 128 + c * 64) * 8]);
        }
        __syncthreads();
        short8 a[4], b[4];
        #pragma unroll
        for (int m = 0; m < 4; m++)
            a[m] = *(const short8*)&Alds[(moff + m * 16 + l16) * 32 + quad * 8];
        #pragma unroll
        for (int n = 0; n < 4; n++)
            b[n] = *(const short8*)&Blds[(noff + n * 16 + l16) * 32 + quad * 8];
        #pragma unroll
        for (int m = 0; m < 4; m++)
            #pragma unroll
            for (int n = 0; n < 4; n++)
                acc[m][n] = MFMA16(a[m], b[n], acc[m][n]);
    }

    if (nbase < 2048) {
        const bool qscale = (nbase < 1024);
        #pragma unroll
        for (int m = 0; m < 4; m++)
            #pragma unroll
            for (int n = 0; n < 4; n++)
                #pragma unroll
                for (int r = 0; r < 4; r++) {
                    int row = mbase + moff + m * 16 + quad * 4 + r;
                    int col = nbase + noff + n * 16 + l16;
                    float v = acc[m][n][r] + bias[col];
                    if (qscale) v *= SCALE_LOG2E;
                    Cq[(size_t)row * D3 + col] = f2bf(v);
                }
    } else {
        // V block: write transposed + key-permuted
        #pragma unroll
        for (int m = 0; m < 4; m++)
            #pragma unroll
            for (int r = 0; r < 4; r++) {
                const int key = mbase + moff + m * 16 + quad * 4 + r;
                const int cp  = (key & ~63) + ((key & 15) * 4 + ((key >> 4) & 3));
                #pragma unroll
                for (int n = 0; n < 4; n++) {
                    const int col = nbase + noff + n * 16 + l16;
                    float v = acc[m][n][r] + bias[col];
                    Vt[(size_t)(col - 2048) * Lq + cp] = f2bf(v);
                }
            }
    }
}

// ---------------- flash attention (R9, unchanged) ----------------
__global__ void __launch_bounds__(512, 2)
attn_fwd(const ushort_t* __restrict__ qkv, const ushort_t* __restrict__ Vt,
         ushort_t* __restrict__ O) {
    __shared__ alignas(16) ushort_t Kl[2][2][64 * 64];   // [half][buf]
    __shared__ alignas(16) ushort_t Vl[2][2][64 * 64];
    __shared__ alignas(16) ushort_t Pl[8 * 32 * 72];
    __shared__ alignas(16) float    Ml[256 * 41];        // merge: pitch 41

    const int tid  = threadIdx.x;
    const int lane = tid & 63;
    const int w    = tid >> 6;          // [0,8)
    const int half = w >> 2;            // 0: even tiles, 1: odd tiles
    const int sub  = w & 3;             // q sub-chunk
    const int quad = lane >> 4;
    const int l16  = lane & 15;
    const int bid  = blockIdx.x;
    const int h    = bid & 15;
    const int p    = bid >> 4;          // [0,16)
    ushort_t* pw   = Pl + w * 32 * 72;
    const float NEG_INF = -__builtin_inff();
    const int sw   = l16 & 7;

    const short bf1 = (short)0x3F80;
    const short8 ones = { bf1, bf1, bf1, bf1, bf1, bf1, bf1, bf1 };

    const ushort_t* kbase = qkv + Dm + h * HD;           // K rows, stride D3
    const ushort_t* vbase = Vt + (size_t)h * HD * Lq;    // V^T rows, stride Lq

    int kvo[4][2];
    #pragma unroll
    for (int s = 0; s < 4; s++)
        #pragma unroll
        for (int kh = 0; kh < 2; kh++)
            kvo[s][kh] = (s * 16 + l16) * 64 + (((kh * 4 + quad) ^ sw) * 8);

    const int rr = tid >> 3, cc = (tid & 7) ^ (rr & 7);
    const ushort_t* kse = kbase + (size_t)rr * D3 + cc * 8;
    const ushort_t* vse = vbase + (size_t)rr * Lq + cc * 8;
    const int dstoff = w * 512;

    for (int sel = 0; sel < 2; sel++) {
        const int c      = sel ? (31 - p) : p;
        const int qc     = c * 128;
        const int rounds = c + 1;
        const int qw     = qc + sub * 32;

        short8 qf[2][2];
        #pragma unroll
        for (int m = 0; m < 2; m++) {
            const ushort_t* qr = qkv + (size_t)(qw + m * 16 + l16) * D3 + h * HD;
            qf[m][0] = *(const short8*)(qr + quad * 8);
            qf[m][1] = *(const short8*)(qr + 32 + quad * 8);
        }

        f32x4 o[2][4] = {};
        f32x4 lacc[2] = {};

        const ushort_t* kp = kse;
        const ushort_t* vp = vse;

        auto stage = [&](int b) {
            gl2lds16(kp,           &Kl[0][b][dstoff]);
            gl2lds16(kp + 64 * D3, &Kl[1][b][dstoff]);
            gl2lds16(vp,           &Vl[0][b][dstoff]);
            gl2lds16(vp + 64,      &Vl[1][b][dstoff]);
            kp += (size_t)128 * D3;
            vp += 128;
        };

        stage(0);

        for (int r = 0; r < rounds; r++) {
            const int buf = r & 1;
            __syncthreads();
            if (r + 1 < rounds) stage(buf ^ 1);

            const ushort_t* Kb = &Kl[half][buf][0];
            const ushort_t* Vb = &Vl[half][buf][0];
            const int k0 = (2 * r + half) * 64;
            const bool domask = (r == rounds - 1);

            short8 kf[4][2];
            #pragma unroll
            for (int s = 0; s < 4; s++)
                #pragma unroll
                for (int kh = 0; kh < 2; kh++)
                    kf[s][kh] = *(const short8*)&Kb[kvo[s][kh]];

            f32x4 st[2][4];
            #pragma unroll
            for (int m = 0; m < 2; m++)
                #pragma unroll
                for (int s = 0; s < 4; s++) {
                    f32x4 t = {};
                    t = MFMA16(qf[m][0], kf[s][0], t);
                    t = MFMA16(qf[m][1], kf[s][1], t);
                    st[m][s] = t;
                }

            #pragma unroll
            for (int m = 0; m < 2; m++)
                #pragma unroll
                for (int r4 = 0; r4 < 4; r4++) {
                    float e[4];
                    #pragma unroll
                    for (int s = 0; s < 4; s++) {
                        float v = st[m][s][r4];
                        if (domask) {
                            const int qg = qw + m * 16 + quad * 4 + r4;
                            if (k0 + s * 16 + l16 > qg) v = NEG_INF;
                        }
                        e[s] = __builtin_amdgcn_exp2f(v);
                    }
                    uint2 pk = { cvtpk(e[0], e[1]), cvtpk(e[2], e[3]) };
                    *(uint2*)&pw[(m * 16 + quad * 4 + r4) * 72 + l16 * 4] = pk;
                }

            short8 pf[2][2];
            #pragma unroll
            for (int m = 0; m < 2; m++)
                #pragma unroll
                for (int kh = 0; kh < 2; kh++)
                    pf[m][kh] = *(const short8*)&pw[(m * 16 + l16) * 72 + kh * 32 + quad * 8];
            #pragma unroll
            for (int m = 0; m < 2; m++) {
                lacc[m] = MFMA16(pf[m][0], ones, lacc[m]);
                lacc[m] = MFMA16(pf[m][1], ones, lacc[m]);
            }

            short8 vf[4][2];
            #pragma unroll
            for (int t = 0; t < 4; t++)
                #pragma unroll
                for (int kh = 0; kh < 2; kh++)
                    vf[t][kh] = *(const short8*)&Vb[kvo[t][kh]];
            #pragma unroll
            for (int m = 0; m < 2; m++)
                #pragma unroll
                for (int t = 0; t < 4; t++) {
                    o[m][t] = MFMA16(pf[m][0], vf[t][0], o[m][t]);
                    o[m][t] = MFMA16(pf[m][1], vf[t][1], o[m][t]);
                }
        }

        __syncthreads();
        if (half == 1) {
            float* dst = Ml + (sub * 64 + lane) * 41;
            #pragma unroll
            for (int m = 0; m < 2; m++)
                #pragma unroll
                for (int t = 0; t < 4; t++)
                    *(f32x4*)(dst + m * 16 + t * 4) = o[m][t];
            *(f32x4*)(dst + 32) = lacc[0];
            *(f32x4*)(dst + 36) = lacc[1];
        }
        __syncthreads();
        if (half == 0) {
            const float* src = Ml + (sub * 64 + lane) * 41;
            #pragma unroll
            for (int m = 0; m < 2; m++)
                #pragma unroll
                for (int t = 0; t < 4; t++)
                    o[m][t] += *(const f32x4*)(src + m * 16 + t * 4);
            lacc[0] += *(const f32x4*)(src + 32);
            lacc[1] += *(const f32x4*)(src + 36);
            #pragma unroll
            for (int m = 0; m < 2; m++)
                #pragma unroll
                for (int r4 = 0; r4 < 4; r4++) {
                    const float inv = 1.0f / lacc[m][r4];
                    ushort_t* orow = O + (size_t)(qw + m * 16 + quad * 4 + r4) * Dm + h * HD;
                    #pragma unroll
                    for (int t = 0; t < 4; t++)
                        orow[t * 16 + l16] = f2bf(o[m][t][r4] * inv);
                }
        }
        __syncthreads();
    }
}

// ---------------- proj GEMM: 128x64 tiles (512 blocks = 2/CU) ----------------
__global__ void __launch_bounds__(256)
gemm_proj(const ushort_t* __restrict__ A, const ushort_t* __restrict__ Bt,
          const float* __restrict__ bias, float* __restrict__ C) {
    __shared__ alignas(16) ushort_t Alds[128 * 32];
    __shared__ alignas(16) ushort_t Blds[64 * 32];
    const int tid  = threadIdx.x;
    const int lane = tid & 63;
    const int w    = tid >> 6;
    const int quad = lane >> 4;
    const int l16  = lane & 15;
    const int mbase = blockIdx.x * 128;
    const int nbase = blockIdx.y * 64;
    const int moff  = (w >> 1) * 64;
    const int noff  = (w & 1) * 32;
    const int K = Dm, N = Dm;

    f32x4 acc[4][2] = {};

    for (int kb = 0; kb < K; kb += 32) {
        __syncthreads();
        #pragma unroll
        for (int c = 0; c < 2; c++) {
            int id  = w * 128 + c * 64 + lane;
            int row = id >> 2, col = (id & 3) * 8;
            gl2lds16(&A[(size_t)(mbase + row) * K + kb + col], &Alds[(size_t)(w * 128 + c * 64) * 8]);
        }
        {
            int id  = w * 64 + lane;
            int row = id >> 2, col = (id & 3) * 8;
            gl2lds16(&Bt[(size_t)(nbase + row) * K + kb + col], &Blds[(size_t)(w * 64) * 8]);
        }
        __syncthreads();
        short8 a[4], b[2];
        #pragma unroll
        for (int m = 0; m < 4; m++)
            a[m] = *(const short8*)&Alds[(moff + m * 16 + l16) * 32 + quad * 8];
        #pragma unroll
        for (int n = 0; n < 2; n++)
            b[n] = *(const short8*)&Blds[(noff + n * 16 + l16) * 32 + quad * 8];
        #pragma unroll
        for (int m = 0; m < 4; m++)
            #pragma unroll
            for (int n = 0; n < 2; n++)
                acc[m][n] = MFMA16(a[m], b[n], acc[m][n]);
    }

    #pragma unroll
    for (int m = 0; m < 4; m++)
        #pragma unroll
        for (int n = 0; n < 2; n++)
            #pragma unroll
            for (int r = 0; r < 4; r++) {
                int row = mbase + moff + m * 16 + quad * 4 + r;
                int col = nbase + noff + n * 16 + l16;
                C[(size_t)row * N + col] = acc[m][n][r] + bias[col];
            }
}

// ---------------- launch ----------------
extern "C" void kernel_launch(void* const* d_in, const int* in_sizes, int n_in,
                              void* d_out, int out_size, void* d_ws, size_t ws_size,
                              hipStream_t stream) {
    const float* X     = (const float*)d_in[0];
    const float* Wqkv  = (const float*)d_in[1];
    const float* bqkv  = (const float*)d_in[2];
    const float* Wproj = (const float*)d_in[3];
    const float* bproj = (const float*)d_in[4];
    float* out = (float*)d_out;

    ushort_t* ws     = (ushort_t*)d_ws;
    ushort_t* Xb     = ws;                               // 4096x1024
    ushort_t* WqkvT  = Xb + (size_t)Lq * Dm;             // 3072x1024
    ushort_t* WprojT = WqkvT + (size_t)D3 * Dm;          // 1024x1024
    ushort_t* qkvB   = WprojT + (size_t)Dm * Dm;         // 4096x3072 (Q,K used)
    ushort_t* VtB    = qkvB + (size_t)Lq * D3;           // 16x64x4096
    ushort_t* Ob     = VtB + (size_t)NH * HD * Lq;       // 4096x1024

    prep<<<dim3(8192), 256, 0, stream>>>(X, Wqkv, Wproj, Xb, WqkvT, WprojT);

    gemm_qkv<<<dim3(Lq / 128, D3 / 128), 256, 0, stream>>>(
        Xb, WqkvT, bqkv, qkvB, VtB);

    attn_fwd<<<dim3(256), 512, 0, stream>>>(qkvB, VtB, Ob);

    gemm_proj<<<dim3(Lq / 128, Dm / 64), 256, 0, stream>>>(
        Ob, WprojT, bproj, out);
}